// Round 4
// baseline (227.790 us; speedup 1.0000x reference)
//
#include <hip/hip_runtime.h>

// CSR-gather pipeline (no float atomics in math paths):
//   memset(bcnt) ; cast_count (x->fp16 + bucket hist) ; bucket_scan (1 blk) ;
//   fill_a ; fill_b2 (per-bucket node hist + scan + ptr/dinv/csr/cidx) ; k_blo
//   (per-block node lower bounds) ; gather32 ; h1tab ; memset(gmax) ;
//   edge_mlp (EDGE-PARALLEL: streaming 16-edge tiles, LDS atomicMax segment-max,
//   fused Wg2 flush) ; bfix (boundary/overflow nodes) ; gcn2_gather
// R4: edge_mlp restructured edge-parallel. Old per-node loop was latency-bound
//     (VALU duty ~6%/wave on a serial ptr->csr->btab chain). Now loads stream,
//     tiles are always full (50k vs 77k), reductions go through an LDS int-max
//     table (relu-clamped fp32 bits; exact). Ownership: node owned by block of
//     its first edge; boundary/overflow nodes finalize via gmax + k_bfix.

typedef __attribute__((ext_vector_type(8))) short short8;
typedef __attribute__((ext_vector_type(4))) float f32x4;
typedef __attribute__((ext_vector_type(8))) _Float16 f16x8;
typedef __attribute__((ext_vector_type(4))) _Float16 f16x4;
typedef __attribute__((ext_vector_type(2))) _Float16 f16x2;

#define FILL_CH 4096      // edges per phase-A block (256 thr x 16)
#define TB_EDGES 512      // edges per edge_mlp block
#define TBL 64            // LDS node-table rows per edge_mlp block

__device__ __forceinline__ unsigned short f2bf(float x) {   // RNE f32->bf16 (cold paths only)
    unsigned int u = __float_as_uint(x);
    return (unsigned short)((u + 0x7FFFu + ((u >> 16) & 1u)) >> 16);
}
__device__ __forceinline__ float bf2f(unsigned short h) {
    return __uint_as_float(((unsigned int)h) << 16);
}
// cheap truncation split: u ~= hi + lo with |err| ~ 2^-16 |u|
__device__ __forceinline__ void splitT(float u, short& hi, short& lo) {
    unsigned int ub = __float_as_uint(u);
    hi = (short)(ub >> 16);
    float r = u - __uint_as_float(ub & 0xFFFF0000u);
    lo = (short)(__float_as_uint(r) >> 16);
}
__device__ __forceinline__ f16x8 relu8(f16x8 v) {
    f16x8 z = {0, 0, 0, 0, 0, 0, 0, 0};
#if __has_builtin(__builtin_elementwise_max)
    return __builtin_elementwise_max(v, z);
#else
    f16x8 o;
#pragma unroll
    for (int j = 0; j < 8; ++j) o[j] = v[j] > (_Float16)0 ? v[j] : (_Float16)0;
    return o;
#endif
}

// rotate-add within a 16-lane row (DPP row_ror:N); tree 1,2,4,8 == full 16-lane
// sum in every lane. Pure VALU. (row_ror = 0x120+N.)
#define ROR_ADD(s, CTRL)                                                         \
    s += __int_as_float(__builtin_amdgcn_update_dpp(                             \
        0, __float_as_int(s), (CTRL), 0xf, 0xf, false))
#define ROR8_ADD(s) ROR_ADD(s, 0x128)

// fused: x -> fp16 cast + bucket-level edge histogram (LDS-aggregated)
__global__ __launch_bounds__(256) void k_cast_count(
        const int* __restrict__ col, const float4* __restrict__ x4,
        f16x4* __restrict__ xh4, int* __restrict__ bcnt, int E, int m4, int nb) {
    __shared__ int cnt[512];
    int tid = threadIdx.x;
    for (int i = tid; i < nb; i += 256) cnt[i] = 0;
    __syncthreads();
    int e0 = blockIdx.x * FILL_CH;
#pragma unroll
    for (int i = 0; i < 16; ++i) {
        int e = e0 + tid + i * 256;
        if (e < E) atomicAdd(&cnt[col[e] >> 7], 1);
    }
    int nth = gridDim.x * 256;
    for (int idx = blockIdx.x * 256 + tid; idx < m4; idx += nth) {
        float4 v = x4[idx];
        f16x4 o;
        o[0] = (_Float16)v.x; o[1] = (_Float16)v.y;
        o[2] = (_Float16)v.z; o[3] = (_Float16)v.w;
        xh4[idx] = o;
    }
    __syncthreads();
    for (int i = tid; i < nb; i += 256)
        if (cnt[i]) atomicAdd(&bcnt[i], cnt[i]);
}

// single block: exclusive scan of nb (<=512) bucket counts -> bbase, bcur
__global__ __launch_bounds__(512) void k_bucket_scan(
        const int* __restrict__ bcnt, int* __restrict__ bbase,
        int* __restrict__ bcur, int* __restrict__ ptr, int nb, int n, int E) {
    __shared__ int wt[8];
    int tid = threadIdx.x;
    int lane = tid & 63, w = tid >> 6;
    int v = (tid < nb) ? bcnt[tid] : 0;
    int s = v;
    for (int off = 1; off < 64; off <<= 1) {
        int t = __shfl_up(s, off, 64);
        if (lane >= off) s += t;
    }
    if (lane == 63) wt[w] = s;
    __syncthreads();
    int pre = 0;
    for (int i = 0; i < 8; ++i) if (i < w) pre += wt[i];
    int excl = pre + s - v;
    if (tid < nb) { bbase[tid] = excl; bcur[tid] = excl; }
    if (tid == nb) bbase[tid] = E;
    if (tid == 0) ptr[n] = E;
}

// fill phase A: bucket edges (128 cols/bucket) into contiguous per-bucket runs
__global__ __launch_bounds__(256) void k_fill_a(const int* __restrict__ row,
                                                const int* __restrict__ col,
                                                int* __restrict__ bcur,
                                                int2* __restrict__ stage, int E, int nb) {
    __shared__ int cnt[512];
    __shared__ int base[512];
    int tid = threadIdx.x;
    int e0 = blockIdx.x * FILL_CH;
    for (int i = tid; i < nb; i += 256) cnt[i] = 0;
    __syncthreads();
    int r[16], c[16];
#pragma unroll
    for (int i = 0; i < 16; ++i) {
        int e = e0 + tid + i * 256;
        if (e < E) {
            r[i] = row[e]; c[i] = col[e];
            atomicAdd(&cnt[c[i] >> 7], 1);
        } else c[i] = -1;
    }
    __syncthreads();
    for (int i = tid; i < nb; i += 256)
        base[i] = cnt[i] ? atomicAdd(&bcur[i], cnt[i]) : 0;
    __syncthreads();
    for (int i = tid; i < nb; i += 256) cnt[i] = 0;
    __syncthreads();
#pragma unroll
    for (int i = 0; i < 16; ++i) {
        if (c[i] >= 0) {
            int b = c[i] >> 7;
            int lp = atomicAdd(&cnt[b], 1);
            stage[base[b] + lp] = make_int2(r[i], c[i]);
        }
    }
}

// fill phase B2: one block per bucket; local 128-col hist + exclusive scan
// produces ptr/dinv for this bucket's nodes, then scatters csr AND cidx.
__global__ __launch_bounds__(256) void k_fill_b2(
        const int* __restrict__ bbase, const int* __restrict__ bcur_end,
        const int2* __restrict__ stage, int* __restrict__ ptr,
        float* __restrict__ dinv, int* __restrict__ csr,
        int* __restrict__ cidx, int n) {
    __shared__ int lcnt[128];
    __shared__ int lcur[128];
    __shared__ int wtotS;
    int b = blockIdx.x, tid = threadIdx.x;
    int c0 = b << 7;
    int start = bbase[b], end = bcur_end[b];
    if (tid < 128) lcnt[tid] = 0;
    __syncthreads();
    for (int p = start + tid; p < end; p += 256)
        atomicAdd(&lcnt[stage[p].y & 127], 1);
    __syncthreads();
    int lane = tid & 63, w = tid >> 6;
    int v = (tid < 128) ? lcnt[tid] : 0;
    int s = v;
    for (int off = 1; off < 64; off <<= 1) {
        int t = __shfl_up(s, off, 64);
        if (lane >= off) s += t;
    }
    if (tid == 63) wtotS = s;
    __syncthreads();
    int excl = s - v + ((w == 1) ? wtotS : 0);
    if (tid < 128) {
        int c = c0 + tid;
        int basep = start + excl;
        lcur[tid] = basep;
        if (c < n) {
            ptr[c] = basep;
            dinv[c] = rsqrtf((float)(v + 1));   // +1 self loop
        }
    }
    __syncthreads();
    for (int p = start + tid; p < end; p += 256) {
        int2 rc = stage[p];
        int pos = atomicAdd(&lcur[rc.y & 127], 1);
        csr[pos] = rc.x;
        cidx[pos] = rc.y;
    }
}

// blo[b] = first node c with ptr[c] >= b*TB_EDGES (blo[nblkE] = n)
__global__ __launch_bounds__(256) void k_blo(const int* __restrict__ ptr,
                                             int* __restrict__ blo, int n, int nblkE) {
    int b = blockIdx.x * 256 + threadIdx.x;
    if (b > nblkE) return;
    if (b == nblkE) { blo[b] = n; return; }
    int target = b * TB_EDGES;
    int lo = 0, hi = n;
    while (lo < hi) {
        int mid = (lo + hi) >> 1;
        if (ptr[mid] < target) lo = mid + 1; else hi = mid;
    }
    blo[b] = lo;
}

// irregular gather (fp16 x): agg[v] = dv*(sum dinv[r]*xh[r]) + dv^2*x[v]
__global__ __launch_bounds__(256) void k_gather32(
        const int* __restrict__ ptr, const int* __restrict__ csr_row,
        const float* __restrict__ x, const _Float16* __restrict__ xh,
        const float* __restrict__ dinv, float* __restrict__ agg, int n) {
    int wid = blockIdx.x * 4 + (threadIdx.x >> 6);
    if (wid >= n) return;
    int lane = threadIdx.x & 63;
    int f4 = lane & 7, slot = lane >> 3;
    int v = wid;
    int start = ptr[v], end = ptr[v + 1];
    const f16x4* xh4 = (const f16x4*)xh;
    float sx = 0.f, sy = 0.f, sz = 0.f, sw = 0.f;
    int p = start + slot;
    int r = (p < end) ? csr_row[p] : 0;
    while (p < end) {
        int rcur = r;
        int pn = p + 8;
        if (pn < end) r = csr_row[pn];
        float dr = dinv[rcur];
        f16x4 xv = xh4[(size_t)rcur * 8 + f4];
        sx = fmaf(dr, (float)xv[0], sx);
        sy = fmaf(dr, (float)xv[1], sy);
        sz = fmaf(dr, (float)xv[2], sz);
        sw = fmaf(dr, (float)xv[3], sw);
        p = pn;
    }
    ROR8_ADD(sx); ROR8_ADD(sy); ROR8_ADD(sz); ROR8_ADD(sw);
#pragma unroll
    for (int off = 16; off < 64; off <<= 1) {
        sx += __shfl_xor(sx, off); sy += __shfl_xor(sy, off);
        sz += __shfl_xor(sz, off); sw += __shfl_xor(sw, off);
    }
    if (slot == 0) {
        float dv = dinv[v], d2 = dv * dv;
        float4 xv = ((const float4*)x)[(size_t)v * 8 + f4];
        float4 o;
        o.x = dv * sx + d2 * xv.x;
        o.y = dv * sy + d2 * xv.y;
        o.z = dv * sz + d2 * xv.z;
        o.w = dv * sw + d2 * xv.w;
        ((float4*)agg)[(size_t)v * 8 + f4] = o;
    }
}

// FUSED dense MFMA: h1 = tanh(agg @ Wg1 + gb) ; atab = h1@(W1a-W1b)+b1 ;
// btab = h1@W1b (fp16 out). Wave-private LDS tile for C/D->A transform.
__global__ __launch_bounds__(256, 1) void k_h1tab(
        const float* __restrict__ agg, const float* __restrict__ gw,
        const float* __restrict__ gb, const float* __restrict__ w1,
        const float* __restrict__ b1,
        _Float16* __restrict__ atab, _Float16* __restrict__ btab, int ntiles) {
    __shared__ float tileS[4][16 * 66];
    int lane = threadIdx.x & 63;
    int wv = threadIdx.x >> 6;
    int n16 = lane & 15, q = lane >> 4;
    float* T = tileS[wv];

    short8 gh[4], gl[4];
    float gbias[4];
#pragma unroll
    for (int t = 0; t < 4; ++t) {
        gbias[t] = gb[t * 16 + n16];
        short8 hh, ll;
#pragma unroll
        for (int j = 0; j < 8; ++j) {
            float w = gw[(q * 8 + j) * 64 + t * 16 + n16];
            unsigned short wh = f2bf(w);
            hh[j] = (short)wh;
            ll[j] = (short)f2bf(w - bf2f(wh));
        }
        gh[t] = hh; gl[t] = ll;
    }
    short8 th[4][2], tl[4][2], uh[4][2], ul[4][2];
    float bias1[4];
#pragma unroll
    for (int t = 0; t < 4; ++t) {
        bias1[t] = b1[t * 16 + n16];
#pragma unroll
        for (int ck = 0; ck < 2; ++ck) {
            short8 h1v, l1v, h2v, l2v;
#pragma unroll
            for (int j = 0; j < 8; ++j) {
                int d = ck * 32 + q * 8 + j;
                float wbv = w1[(64 + d) * 64 + t * 16 + n16];
                float wtv = w1[d * 64 + t * 16 + n16] - wbv;
                unsigned short x1 = f2bf(wtv);
                h1v[j] = (short)x1; l1v[j] = (short)f2bf(wtv - bf2f(x1));
                unsigned short x2 = f2bf(wbv);
                h2v[j] = (short)x2; l2v[j] = (short)f2bf(wbv - bf2f(x2));
            }
            th[t][ck] = h1v; tl[t][ck] = l1v;
            uh[t][ck] = h2v; ul[t][ck] = l2v;
        }
    }

    int nwaves = gridDim.x * 4;
    int wid = blockIdx.x * 4 + wv;
    for (int tile = wid; tile < ntiles; tile += nwaves) {
        int v0 = tile * 16;
        const float4* a4 = (const float4*)(agg + (size_t)(v0 + n16) * 32);
        float4 A0 = a4[2 * q], A1 = a4[2 * q + 1];
        float a[8] = {A0.x, A0.y, A0.z, A0.w, A1.x, A1.y, A1.z, A1.w};
        short8 ah, al;
#pragma unroll
        for (int j = 0; j < 8; ++j) { short h, l; splitT(a[j], h, l); ah[j] = h; al[j] = l; }
#pragma unroll
        for (int t = 0; t < 4; ++t) {
            f32x4 acc = (f32x4){gbias[t], gbias[t], gbias[t], gbias[t]};
            acc = __builtin_amdgcn_mfma_f32_16x16x32_bf16(ah, gh[t], acc, 0, 0, 0);
            acc = __builtin_amdgcn_mfma_f32_16x16x32_bf16(al, gh[t], acc, 0, 0, 0);
            acc = __builtin_amdgcn_mfma_f32_16x16x32_bf16(ah, gl[t], acc, 0, 0, 0);
#pragma unroll
            for (int i = 0; i < 4; ++i)
                T[(q * 4 + i) * 66 + t * 16 + n16] = tanhf(acc[i]);
        }
        float b[16];
#pragma unroll
        for (int j = 0; j < 8; ++j) {
            b[j]     = T[n16 * 66 + q * 8 + j];
            b[8 + j] = T[n16 * 66 + 32 + q * 8 + j];
        }
        short8 ah0, ah1, al0, al1;
#pragma unroll
        for (int j = 0; j < 8; ++j) {
            short h, l;
            splitT(b[j], h, l);      ah0[j] = h; al0[j] = l;
            splitT(b[8 + j], h, l);  ah1[j] = h; al1[j] = l;
        }
#pragma unroll
        for (int t = 0; t < 4; ++t) {
            f32x4 aa = (f32x4){bias1[t], bias1[t], bias1[t], bias1[t]};
            aa = __builtin_amdgcn_mfma_f32_16x16x32_bf16(ah0, th[t][0], aa, 0, 0, 0);
            aa = __builtin_amdgcn_mfma_f32_16x16x32_bf16(ah1, th[t][1], aa, 0, 0, 0);
            aa = __builtin_amdgcn_mfma_f32_16x16x32_bf16(al0, th[t][0], aa, 0, 0, 0);
            aa = __builtin_amdgcn_mfma_f32_16x16x32_bf16(al1, th[t][1], aa, 0, 0, 0);
            aa = __builtin_amdgcn_mfma_f32_16x16x32_bf16(ah0, tl[t][0], aa, 0, 0, 0);
            aa = __builtin_amdgcn_mfma_f32_16x16x32_bf16(ah1, tl[t][1], aa, 0, 0, 0);
            f32x4 bb = (f32x4){0.f, 0.f, 0.f, 0.f};
            bb = __builtin_amdgcn_mfma_f32_16x16x32_bf16(ah0, uh[t][0], bb, 0, 0, 0);
            bb = __builtin_amdgcn_mfma_f32_16x16x32_bf16(ah1, uh[t][1], bb, 0, 0, 0);
            bb = __builtin_amdgcn_mfma_f32_16x16x32_bf16(al0, uh[t][0], bb, 0, 0, 0);
            bb = __builtin_amdgcn_mfma_f32_16x16x32_bf16(al1, uh[t][1], bb, 0, 0, 0);
            bb = __builtin_amdgcn_mfma_f32_16x16x32_bf16(ah0, ul[t][0], bb, 0, 0, 0);
            bb = __builtin_amdgcn_mfma_f32_16x16x32_bf16(ah1, ul[t][1], bb, 0, 0, 0);
#pragma unroll
            for (int i = 0; i < 4; ++i) {
                size_t off = (size_t)(v0 + q * 4 + i) * 64 + t * 16 + n16;
                atab[off] = (_Float16)aa[i];
                btab[off] = (_Float16)bb[i];
            }
        }
    }
}

// EDGE-PARALLEL edge MLP + segment-max + fused GCN2 matmul.
// Block b owns edges [b*TB_EDGES, min((b+1)*TB_EDGES, E)) and nodes whose FIRST
// edge lies in that range ([blo[b], blo[b+1])). Per-tile m values are
// relu-clamped and max-combined into an LDS int table (fp32 bits, exact max).
// Interior owned nodes: h2h = tbl_row @ Wg2 written directly. Boundary (edge
// range crosses a block boundary) or table-overflow nodes: partials pushed to
// gmax (global int atomicMax); k_bfix finalizes them.
__global__ __launch_bounds__(256) void k_edge_mlp(
        const int* __restrict__ csr_row, const int* __restrict__ cidx,
        const int* __restrict__ ptr, const int* __restrict__ blo,
        const _Float16* __restrict__ atab, const _Float16* __restrict__ btab,
        const float* __restrict__ w2, const float* __restrict__ b2,
        const float* __restrict__ wg, int* __restrict__ gmax,
        _Float16* __restrict__ h2h, int n, int E) {
    __shared__ int tbl[TBL * 64];
    int tid = threadIdx.x, lane = tid & 63, wv = tid >> 6;
    int n16 = lane & 15, q = lane >> 4;
    int b = blockIdx.x;
    int e0b = b * TB_EDGES;
    int eend = min(e0b + TB_EDGES, E);
    int cb = cidx[e0b];

    // W2 frags + bias
    f16x8 wh[4][2];
    float bias[4];
#pragma unroll
    for (int t = 0; t < 4; ++t) {
        bias[t] = b2[t * 16 + n16];
#pragma unroll
        for (int ck = 0; ck < 2; ++ck) {
            f16x8 hh;
#pragma unroll
            for (int j = 0; j < 8; ++j)
                hh[j] = (_Float16)w2[(ck * 32 + q * 8 + j) * 64 + t * 16 + n16];
            wh[t][ck] = hh;
        }
    }

    for (int i = tid; i < TBL * 64; i += 256) tbl[i] = 0;
    __syncthreads();

    int ntile = (eend - e0b + 15) >> 4;
    int ti = wv;
    if (ti < ntile) {
        int ec = e0b + ti * 16 + n16;
        if (ec >= eend) ec = eend - 1;
        int r = csr_row[ec], cv = cidx[ec];
        while (ti < ntile) {
            int e0 = e0b + ti * 16;
            int cvK = cv;
            const f16x8* a8 = (const f16x8*)(atab + (size_t)cv * 64);
            const f16x8* b8 = (const f16x8*)(btab + (size_t)r * 64);
            f16x8 u0 = relu8(a8[q] + b8[q]);
            f16x8 u1 = relu8(a8[4 + q] + b8[4 + q]);
            // prefetch next tile's csr/cidx (independent addresses)
            int tin = ti + 4;
            if (tin < ntile) {
                int ec2 = e0b + tin * 16 + n16;
                if (ec2 >= eend) ec2 = eend - 1;
                r = csr_row[ec2]; cv = cidx[ec2];
            }
            f32x4 acc[4];
#pragma unroll
            for (int t = 0; t < 4; ++t) {
                f32x4 a = (f32x4){bias[t], bias[t], bias[t], bias[t]};
                a = __builtin_amdgcn_mfma_f32_16x16x32_f16(u0, wh[t][0], a, 0, 0, 0);
                a = __builtin_amdgcn_mfma_f32_16x16x32_f16(u1, wh[t][1], a, 0, 0, 0);
                acc[t] = a;
            }
            // ---- segment-max combine: rows q*4+i are edges, col n16+16t feats
            int c0l = __shfl(cvK, 0);
            bool uni = __all(cvK == c0l) && (e0 + 15 < eend);
            if (uni) {
                float rr[4];
#pragma unroll
                for (int t = 0; t < 4; ++t) {
                    float m = fmaxf(fmaxf(acc[t][0], acc[t][1]),
                                    fmaxf(acc[t][2], acc[t][3]));
                    m = fmaxf(m, __shfl_xor(m, 16));
                    m = fmaxf(m, __shfl_xor(m, 32));
                    rr[t] = fmaxf(m, 0.f);
                }
                if (q == 0) {
                    int ix = c0l - cb;
                    if ((unsigned)ix < (unsigned)TBL) {
#pragma unroll
                        for (int t = 0; t < 4; ++t)
                            atomicMax(&tbl[ix * 64 + t * 16 + n16], __float_as_int(rr[t]));
                    } else {
#pragma unroll
                        for (int t = 0; t < 4; ++t)
                            atomicMax(&gmax[(size_t)c0l * 64 + t * 16 + n16],
                                      __float_as_int(rr[t]));
                    }
                }
            } else {
                int cc0 = __shfl(cvK, q * 4 + 0);
                int cc1 = __shfl(cvK, q * 4 + 1);
                int cc2 = __shfl(cvK, q * 4 + 2);
                int cc3 = __shfl(cvK, q * 4 + 3);
                int e0q = e0 + q * 4;
                float m[4];
                int cur = cc0;
                bool any = e0q < eend;
#pragma unroll
                for (int t = 0; t < 4; ++t) m[t] = fmaxf(acc[t][0], 0.f);
                auto FLUSH = [&](int c) {
                    int ix = c - cb;
                    if ((unsigned)ix < (unsigned)TBL) {
#pragma unroll
                        for (int t = 0; t < 4; ++t)
                            atomicMax(&tbl[ix * 64 + t * 16 + n16], __float_as_int(m[t]));
                    } else {
#pragma unroll
                        for (int t = 0; t < 4; ++t)
                            atomicMax(&gmax[(size_t)c * 64 + t * 16 + n16],
                                      __float_as_int(m[t]));
                    }
                };
                if (e0q + 1 < eend) {
                    if (cc1 == cur) {
#pragma unroll
                        for (int t = 0; t < 4; ++t) m[t] = fmaxf(m[t], acc[t][1]);
                    } else {
                        FLUSH(cur); cur = cc1;
#pragma unroll
                        for (int t = 0; t < 4; ++t) m[t] = fmaxf(acc[t][1], 0.f);
                    }
                }
                if (e0q + 2 < eend) {
                    if (cc2 == cur) {
#pragma unroll
                        for (int t = 0; t < 4; ++t) m[t] = fmaxf(m[t], acc[t][2]);
                    } else {
                        FLUSH(cur); cur = cc2;
#pragma unroll
                        for (int t = 0; t < 4; ++t) m[t] = fmaxf(acc[t][2], 0.f);
                    }
                }
                if (e0q + 3 < eend) {
                    if (cc3 == cur) {
#pragma unroll
                        for (int t = 0; t < 4; ++t) m[t] = fmaxf(m[t], acc[t][3]);
                    } else {
                        FLUSH(cur); cur = cc3;
#pragma unroll
                        for (int t = 0; t < 4; ++t) m[t] = fmaxf(acc[t][3], 0.f);
                    }
                }
                if (any) {
#pragma unroll
                    for (int t = 0; t < 4; ++t) m[t] = fmaxf(m[t], 0.f);
                    FLUSH(cur);
                }
            }
            ti = tin;
        }
    }
    __syncthreads();

    // ---- flush phase: owned nodes [clo, chi); table covers [cb, cb+TBL)
    int clo = blo[b], chi = blo[b + 1];
    int tmax = min(chi, cb + TBL);
    for (int c = cb + wv * 4 + q; c < tmax; c += 16) {
        int idx = c - cb;
        int st = ptr[c], ed = ptr[c + 1];
        bool bound = (c < clo) ||
                     (ed > st && (st / TB_EDGES != (ed - 1) / TB_EDGES));
        if (!bound) {
            // interior owned (incl. deg-0): h2 = tbl_row @ Wg2
            float s = 0.f;
#pragma unroll
            for (int d = 0; d < 64; ++d)
                s = fmaf(__int_as_float(tbl[idx * 64 + d]), wg[d * 16 + n16], s);
            h2h[(size_t)c * 16 + n16] = (_Float16)s;
        } else {
            // boundary-owned or leading non-owned: push partial to gmax
#pragma unroll
            for (int t = 0; t < 4; ++t)
                atomicMax(&gmax[(size_t)c * 64 + t * 16 + n16],
                          tbl[idx * 64 + t * 16 + n16]);
        }
    }
}

// finalize boundary/overflow nodes: h2h[c] = gmax_row(c) @ Wg2
__global__ __launch_bounds__(256) void k_bfix(
        const int* __restrict__ ptr, const int* __restrict__ cidx,
        const int* __restrict__ gmax, const float* __restrict__ wg,
        _Float16* __restrict__ h2h, int n, int nblkE) {
    int t = blockIdx.x * 256 + threadIdx.x;
    int c = t >> 4, j = t & 15;
    if (c >= n) return;
    int st = ptr[c], ed = ptr[c + 1];
    bool need = (ed > st) && (st / TB_EDGES != (ed - 1) / TB_EDGES);
    if (!need) {
        int owner = st / TB_EDGES;
        if (owner >= nblkE) owner = nblkE - 1;
        need = (c - cidx[owner * TB_EDGES]) >= TBL;
    }
    if (!need) return;
    float s = 0.f;
#pragma unroll
    for (int d = 0; d < 64; ++d)
        s = fmaf(__int_as_float(gmax[(size_t)c * 64 + d]), wg[d * 16 + j], s);
    h2h[(size_t)c * 16 + j] = (_Float16)s;
}

// out[c] = bg + dv*(dv*h2[c] + sum_in dinv[r]*h2[r]) ; fully writes d_out
__global__ __launch_bounds__(256) void k_gcn2_gather(
        const int* __restrict__ ptr, const int* __restrict__ csr_row,
        const _Float16* __restrict__ h2h, const float* __restrict__ dinv,
        const float* __restrict__ bg, float* __restrict__ out, int n) {
    int wid = blockIdx.x * 4 + (threadIdx.x >> 6);
    if (wid >= n) return;
    int lane = threadIdx.x & 63;
    int f2 = lane & 7, slot = lane >> 3;
    int c = wid;
    int start = ptr[c], end = ptr[c + 1];
    const f16x2* h22 = (const f16x2*)h2h;
    float sx = 0.f, sy = 0.f;
    int p = start + slot;
    int r = (p < end) ? csr_row[p] : 0;
    while (p < end) {
        int rcur = r;
        int pn = p + 8;
        if (pn < end) r = csr_row[pn];
        float dr = dinv[rcur];
        f16x2 hv = h22[(size_t)rcur * 8 + f2];
        sx = fmaf(dr, (float)hv[0], sx);
        sy = fmaf(dr, (float)hv[1], sy);
        p = pn;
    }
    ROR8_ADD(sx); ROR8_ADD(sy);
#pragma unroll
    for (int off = 16; off < 64; off <<= 1) {
        sx += __shfl_xor(sx, off);
        sy += __shfl_xor(sy, off);
    }
    if (slot == 0) {
        float dv = dinv[c];
        f16x2 hv = h22[(size_t)c * 8 + f2];
        float2 o;
        o.x = bg[2 * f2]     + dv * (dv * (float)hv[0] + sx);
        o.y = bg[2 * f2 + 1] + dv * (dv * (float)hv[1] + sy);
        ((float2*)out)[(size_t)c * 8 + f2] = o;
    }
}

extern "C" void kernel_launch(void* const* d_in, const int* in_sizes, int n_in,
                              void* d_out, int out_size, void* d_ws, size_t ws_size,
                              hipStream_t stream) {
    const float* x   = (const float*)d_in[0];
    const int*   ei  = (const int*)d_in[1];
    const float* g1w = (const float*)d_in[2];
    const float* g1b = (const float*)d_in[3];
    const float* ew1 = (const float*)d_in[4];
    const float* eb1 = (const float*)d_in[5];
    const float* ew2 = (const float*)d_in[6];
    const float* eb2 = (const float*)d_in[7];
    const float* g2w = (const float*)d_in[8];
    const float* g2b = (const float*)d_in[9];
    float* out = (float*)d_out;
    float* ws  = (float*)d_ws;

    const int n = in_sizes[0] / 32;      // 50000
    const int E = in_sizes[1] / 2;       // 800000
    const int* row = ei;
    const int* col = ei + E;
    const int ntiles = (n + 15) / 16;    // 3125
    const int nbuck = (n + 127) >> 7;    // 391 buckets of 128 cols
    const int nblkE = (E + TB_EDGES - 1) / TB_EDGES;   // 1563 edge blocks

    size_t npad    = ((size_t)n + 63) & ~(size_t)63;
    size_t o_misc  = 0;                          // bcnt[512]+bbase[512]
    size_t o_ptr   = 1024;                       // n+1 (+pad)
    size_t o_csr   = o_ptr + npad + 64;          // E ints
    size_t o_dinv  = o_csr + (size_t)E;
    size_t o_atab  = o_dinv + npad;              // n*64 fp16 = n*32 floats
    size_t o_btab  = o_atab + (size_t)n * 32;    // n*64 fp16
    size_t o_h2h   = o_btab + (size_t)n * 32;    // n*16 fp16 = n*8 floats
    size_t o_agg   = o_h2h + (size_t)n * 8;      // n*32 fp32 ; gmax aliases here
    size_t o_xh    = o_agg + (size_t)n * 32;     // n*32 fp16 = n*16 floats
    size_t o_stage = o_xh + (size_t)n * 16;      // E int2 (dead after fill_b2)
    size_t o_bcur  = o_stage + (size_t)E * 2;    // nbuck ints
    size_t o_blo   = o_bcur + 512;               // nblkE+1 ints (<2048)
    size_t o_cidx  = o_blo + 2048;               // E ints

    int*      bcnt   = (int*)(ws + o_misc);
    int*      bbase  = (int*)(ws + o_misc) + 512;
    int*      ptr    = (int*)(ws + o_ptr);
    int*      csr    = (int*)(ws + o_csr);
    float*    dinv   = ws + o_dinv;
    _Float16* atab   = (_Float16*)(ws + o_atab);
    _Float16* btab   = (_Float16*)(ws + o_btab);
    _Float16* h2h    = (_Float16*)(ws + o_h2h);
    float*    agg    = ws + o_agg;
    int*      gmax   = (int*)(ws + o_agg);       // n*64 ints, alias agg+xh+stage
    _Float16* xh     = (_Float16*)(ws + o_xh);
    int2*     stage  = (int2*)(ws + o_stage);
    int*      bcur   = (int*)(ws + o_bcur);
    int*      blo    = (int*)(ws + o_blo);
    int*      cidx   = (int*)(ws + o_cidx);

    int nblk = (n + 3) / 4;                      // wave-per-node kernels
    int fill_nb = (E + FILL_CH - 1) / FILL_CH;   // 196
    int m4 = n * 8;                              // x float4 count

    hipMemsetAsync(bcnt, 0, 512 * sizeof(int), stream);
    k_cast_count<<<fill_nb, 256, 0, stream>>>(col, (const float4*)x, (f16x4*)xh,
                                              bcnt, E, m4, nbuck);
    k_bucket_scan<<<1, 512, 0, stream>>>(bcnt, bbase, bcur, ptr, nbuck, n, E);
    k_fill_a<<<fill_nb, 256, 0, stream>>>(row, col, bcur, stage, E, nbuck);
    k_fill_b2<<<nbuck, 256, 0, stream>>>(bbase, bcur, stage, ptr, dinv, csr, cidx, n);
    k_blo<<<(nblkE + 256) / 256, 256, 0, stream>>>(ptr, blo, n, nblkE);
    k_gather32<<<nblk, 256, 0, stream>>>(ptr, csr, x, xh, dinv, agg, n);
    k_h1tab<<<256, 256, 0, stream>>>(agg, g1w, g1b, ew1, eb1, atab, btab, ntiles);
    hipMemsetAsync(gmax, 0, (size_t)n * 64 * sizeof(int), stream);   // agg/xh dead
    k_edge_mlp<<<nblkE, 256, 0, stream>>>(csr, cidx, ptr, blo, atab, btab,
                                          ew2, eb2, g2w, gmax, h2h, n, E);
    k_bfix<<<(n * 16 + 255) / 256, 256, 0, stream>>>(ptr, cidx, gmax, g2w, h2h,
                                                     n, nblkE);
    k_gcn2_gather<<<nblk, 256, 0, stream>>>(ptr, csr, h2h, dinv, g2b, out, n);
}

// Round 5
// 223.687 us; speedup vs baseline: 1.0183x; 1.0183x over previous
//
#include <hip/hip_runtime.h>

// CSR-gather pipeline (no float atomics):
//   cast_count (x->fp16 + per-block bucket hist partials) ; bucket_scan (1 blk,
//   sums partials) ; fill_a (packed stage) ; fill_b2 (per-bucket node hist +
//   scan + ptr/dinv/csr) ; gather32 ; h1tab ; edge_mlp (R3 node loop + csr
//   hoist + zero-C MFMA + setprio) ; gcn2_gather
// R5: base = R3 (200.9us). edge_mlp stays <=64 VGPR (occupancy cliff measured
//     R1 vs R3: 72 VGPR halves waves/SIMD). Remainder-csr hoisted to node start
//     (dominant deg 16-31 case: both csr loads issue together); bias folded
//     after row-max (kills 16 splat movs/tile); s_setprio around MFMA.
//     Build: no memset/global-atomic hist (per-block partials), stage packed
//     (r<<7|c&127) halving stage traffic.

typedef __attribute__((ext_vector_type(8))) short short8;
typedef __attribute__((ext_vector_type(4))) float f32x4;
typedef __attribute__((ext_vector_type(8))) _Float16 f16x8;
typedef __attribute__((ext_vector_type(4))) _Float16 f16x4;
typedef __attribute__((ext_vector_type(2))) _Float16 f16x2;

#define FILL_CH 4096      // edges per phase-A block (256 thr x 16)

__device__ __forceinline__ unsigned short f2bf(float x) {   // RNE f32->bf16 (cold paths only)
    unsigned int u = __float_as_uint(x);
    return (unsigned short)((u + 0x7FFFu + ((u >> 16) & 1u)) >> 16);
}
__device__ __forceinline__ float bf2f(unsigned short h) {
    return __uint_as_float(((unsigned int)h) << 16);
}
// cheap truncation split: u ~= hi + lo with |err| ~ 2^-16 |u|
__device__ __forceinline__ void splitT(float u, short& hi, short& lo) {
    unsigned int ub = __float_as_uint(u);
    hi = (short)(ub >> 16);
    float r = u - __uint_as_float(ub & 0xFFFF0000u);
    lo = (short)(__float_as_uint(r) >> 16);
}
__device__ __forceinline__ f16x8 relu8(f16x8 v) {
    f16x8 z = {0, 0, 0, 0, 0, 0, 0, 0};
#if __has_builtin(__builtin_elementwise_max)
    return __builtin_elementwise_max(v, z);
#else
    f16x8 o;
#pragma unroll
    for (int j = 0; j < 8; ++j) o[j] = v[j] > (_Float16)0 ? v[j] : (_Float16)0;
    return o;
#endif
}

// rotate-add within a 16-lane row (DPP row_ror:N); tree 1,2,4,8 == full 16-lane
// sum in every lane. Pure VALU. (row_ror = 0x120+N.)
#define ROR_ADD(s, CTRL)                                                         \
    s += __int_as_float(__builtin_amdgcn_update_dpp(                             \
        0, __float_as_int(s), (CTRL), 0xf, 0xf, false))
#define ROR8_ADD(s) ROR_ADD(s, 0x128)

// fused: x -> fp16 cast + per-block bucket histogram partials (no global atomics)
__global__ __launch_bounds__(256) void k_cast_count(
        const int* __restrict__ col, const float4* __restrict__ x4,
        f16x4* __restrict__ xh4, int* __restrict__ pcnt, int E, int m4, int nb) {
    __shared__ int cnt[512];
    int tid = threadIdx.x;
    for (int i = tid; i < 512; i += 256) cnt[i] = 0;
    __syncthreads();
    int e0 = blockIdx.x * FILL_CH;
#pragma unroll
    for (int i = 0; i < 16; ++i) {
        int e = e0 + tid + i * 256;
        if (e < E) atomicAdd(&cnt[col[e] >> 7], 1);
    }
    int nth = gridDim.x * 256;
    for (int idx = blockIdx.x * 256 + tid; idx < m4; idx += nth) {
        float4 v = x4[idx];
        f16x4 o;
        o[0] = (_Float16)v.x; o[1] = (_Float16)v.y;
        o[2] = (_Float16)v.z; o[3] = (_Float16)v.w;
        xh4[idx] = o;
    }
    __syncthreads();
    for (int i = tid; i < 512; i += 256)
        pcnt[blockIdx.x * 512 + i] = cnt[i];
}

// single block: sum per-block partials, exclusive scan -> bbase, bcur
__global__ __launch_bounds__(512) void k_bucket_scan(
        const int* __restrict__ pcnt, int nchunks, int* __restrict__ bbase,
        int* __restrict__ bcur, int* __restrict__ ptr, int nb, int n, int E) {
    __shared__ int wt[8];
    int tid = threadIdx.x;
    int lane = tid & 63, w = tid >> 6;
    int v = 0;
    for (int k = 0; k < nchunks; ++k) v += pcnt[k * 512 + tid];
    int s = v;
    for (int off = 1; off < 64; off <<= 1) {
        int t = __shfl_up(s, off, 64);
        if (lane >= off) s += t;
    }
    if (lane == 63) wt[w] = s;
    __syncthreads();
    int pre = 0;
    for (int i = 0; i < 8; ++i) if (i < w) pre += wt[i];
    int excl = pre + s - v;
    if (tid < nb) { bbase[tid] = excl; bcur[tid] = excl; }
    if (tid == nb) bbase[tid] = E;
    if (tid == 0) ptr[n] = E;
}

// fill phase A: bucket edges (128 cols/bucket) into contiguous per-bucket runs.
// stage entry packed: (r << 7) | (c & 127)   [valid for n < 2^25]
__global__ __launch_bounds__(256) void k_fill_a(const int* __restrict__ row,
                                                const int* __restrict__ col,
                                                int* __restrict__ bcur,
                                                int* __restrict__ stage, int E, int nb) {
    __shared__ int cnt[512];
    __shared__ int base[512];
    int tid = threadIdx.x;
    int e0 = blockIdx.x * FILL_CH;
    for (int i = tid; i < nb; i += 256) cnt[i] = 0;
    __syncthreads();
    int r[16], c[16];
#pragma unroll
    for (int i = 0; i < 16; ++i) {
        int e = e0 + tid + i * 256;
        if (e < E) {
            r[i] = row[e]; c[i] = col[e];
            atomicAdd(&cnt[c[i] >> 7], 1);
        } else c[i] = -1;
    }
    __syncthreads();
    for (int i = tid; i < nb; i += 256)
        base[i] = cnt[i] ? atomicAdd(&bcur[i], cnt[i]) : 0;
    __syncthreads();
    for (int i = tid; i < nb; i += 256) cnt[i] = 0;
    __syncthreads();
#pragma unroll
    for (int i = 0; i < 16; ++i) {
        if (c[i] >= 0) {
            int b = c[i] >> 7;
            int lp = atomicAdd(&cnt[b], 1);
            stage[base[b] + lp] = (r[i] << 7) | (c[i] & 127);
        }
    }
}

// fill phase B2: one block per bucket; local 128-col hist + exclusive scan
// produces ptr/dinv for this bucket's nodes, then scatters csr via LDS cursors.
__global__ __launch_bounds__(256) void k_fill_b2(
        const int* __restrict__ bbase, const int* __restrict__ bcur_end,
        const int* __restrict__ stage, int* __restrict__ ptr,
        float* __restrict__ dinv, int* __restrict__ csr, int n) {
    __shared__ int lcnt[128];
    __shared__ int lcur[128];
    __shared__ int wtotS;
    int b = blockIdx.x, tid = threadIdx.x;
    int c0 = b << 7;
    int start = bbase[b], end = bcur_end[b];
    if (tid < 128) lcnt[tid] = 0;
    __syncthreads();
    for (int p = start + tid; p < end; p += 256)
        atomicAdd(&lcnt[stage[p] & 127], 1);
    __syncthreads();
    int lane = tid & 63, w = tid >> 6;
    int v = (tid < 128) ? lcnt[tid] : 0;
    int s = v;
    for (int off = 1; off < 64; off <<= 1) {
        int t = __shfl_up(s, off, 64);
        if (lane >= off) s += t;
    }
    if (tid == 63) wtotS = s;
    __syncthreads();
    int excl = s - v + ((w == 1) ? wtotS : 0);
    if (tid < 128) {
        int c = c0 + tid;
        int basep = start + excl;
        lcur[tid] = basep;
        if (c < n) {
            ptr[c] = basep;
            dinv[c] = rsqrtf((float)(v + 1));   // +1 self loop
        }
    }
    __syncthreads();
    for (int p = start + tid; p < end; p += 256) {
        int vv = stage[p];
        int pos = atomicAdd(&lcur[vv & 127], 1);
        csr[pos] = vv >> 7;
    }
}

// irregular gather (fp16 x): agg[v] = dv*(sum dinv[r]*xh[r]) + dv^2*x[v]
__global__ __launch_bounds__(256) void k_gather32(
        const int* __restrict__ ptr, const int* __restrict__ csr_row,
        const float* __restrict__ x, const _Float16* __restrict__ xh,
        const float* __restrict__ dinv, float* __restrict__ agg, int n) {
    int wid = blockIdx.x * 4 + (threadIdx.x >> 6);
    if (wid >= n) return;
    int lane = threadIdx.x & 63;
    int f4 = lane & 7, slot = lane >> 3;
    int v = wid;
    int start = ptr[v], end = ptr[v + 1];
    const f16x4* xh4 = (const f16x4*)xh;
    float sx = 0.f, sy = 0.f, sz = 0.f, sw = 0.f;
    int p = start + slot;
    int r = (p < end) ? csr_row[p] : 0;
    while (p < end) {
        int rcur = r;
        int pn = p + 8;
        if (pn < end) r = csr_row[pn];
        float dr = dinv[rcur];
        f16x4 xv = xh4[(size_t)rcur * 8 + f4];
        sx = fmaf(dr, (float)xv[0], sx);
        sy = fmaf(dr, (float)xv[1], sy);
        sz = fmaf(dr, (float)xv[2], sz);
        sw = fmaf(dr, (float)xv[3], sw);
        p = pn;
    }
    ROR8_ADD(sx); ROR8_ADD(sy); ROR8_ADD(sz); ROR8_ADD(sw);
#pragma unroll
    for (int off = 16; off < 64; off <<= 1) {
        sx += __shfl_xor(sx, off); sy += __shfl_xor(sy, off);
        sz += __shfl_xor(sz, off); sw += __shfl_xor(sw, off);
    }
    if (slot == 0) {
        float dv = dinv[v], d2 = dv * dv;
        float4 xv = ((const float4*)x)[(size_t)v * 8 + f4];
        float4 o;
        o.x = dv * sx + d2 * xv.x;
        o.y = dv * sy + d2 * xv.y;
        o.z = dv * sz + d2 * xv.z;
        o.w = dv * sw + d2 * xv.w;
        ((float4*)agg)[(size_t)v * 8 + f4] = o;
    }
}

// FUSED dense MFMA: h1 = tanh(agg @ Wg1 + gb) ; atab = h1@(W1a-W1b)+b1 ;
// btab = h1@W1b (fp16 out). Wave-private LDS tile for C/D->A transform.
__global__ __launch_bounds__(256, 1) void k_h1tab(
        const float* __restrict__ agg, const float* __restrict__ gw,
        const float* __restrict__ gb, const float* __restrict__ w1,
        const float* __restrict__ b1,
        _Float16* __restrict__ atab, _Float16* __restrict__ btab, int ntiles) {
    __shared__ float tileS[4][16 * 66];
    int lane = threadIdx.x & 63;
    int wv = threadIdx.x >> 6;
    int n16 = lane & 15, q = lane >> 4;
    float* T = tileS[wv];

    short8 gh[4], gl[4];
    float gbias[4];
#pragma unroll
    for (int t = 0; t < 4; ++t) {
        gbias[t] = gb[t * 16 + n16];
        short8 hh, ll;
#pragma unroll
        for (int j = 0; j < 8; ++j) {
            float w = gw[(q * 8 + j) * 64 + t * 16 + n16];
            unsigned short wh = f2bf(w);
            hh[j] = (short)wh;
            ll[j] = (short)f2bf(w - bf2f(wh));
        }
        gh[t] = hh; gl[t] = ll;
    }
    short8 th[4][2], tl[4][2], uh[4][2], ul[4][2];
    float bias1[4];
#pragma unroll
    for (int t = 0; t < 4; ++t) {
        bias1[t] = b1[t * 16 + n16];
#pragma unroll
        for (int ck = 0; ck < 2; ++ck) {
            short8 h1v, l1v, h2v, l2v;
#pragma unroll
            for (int j = 0; j < 8; ++j) {
                int d = ck * 32 + q * 8 + j;
                float wbv = w1[(64 + d) * 64 + t * 16 + n16];
                float wtv = w1[d * 64 + t * 16 + n16] - wbv;
                unsigned short x1 = f2bf(wtv);
                h1v[j] = (short)x1; l1v[j] = (short)f2bf(wtv - bf2f(x1));
                unsigned short x2 = f2bf(wbv);
                h2v[j] = (short)x2; l2v[j] = (short)f2bf(wbv - bf2f(x2));
            }
            th[t][ck] = h1v; tl[t][ck] = l1v;
            uh[t][ck] = h2v; ul[t][ck] = l2v;
        }
    }

    int nwaves = gridDim.x * 4;
    int wid = blockIdx.x * 4 + wv;
    for (int tile = wid; tile < ntiles; tile += nwaves) {
        int v0 = tile * 16;
        const float4* a4 = (const float4*)(agg + (size_t)(v0 + n16) * 32);
        float4 A0 = a4[2 * q], A1 = a4[2 * q + 1];
        float a[8] = {A0.x, A0.y, A0.z, A0.w, A1.x, A1.y, A1.z, A1.w};
        short8 ah, al;
#pragma unroll
        for (int j = 0; j < 8; ++j) { short h, l; splitT(a[j], h, l); ah[j] = h; al[j] = l; }
#pragma unroll
        for (int t = 0; t < 4; ++t) {
            f32x4 acc = (f32x4){gbias[t], gbias[t], gbias[t], gbias[t]};
            acc = __builtin_amdgcn_mfma_f32_16x16x32_bf16(ah, gh[t], acc, 0, 0, 0);
            acc = __builtin_amdgcn_mfma_f32_16x16x32_bf16(al, gh[t], acc, 0, 0, 0);
            acc = __builtin_amdgcn_mfma_f32_16x16x32_bf16(ah, gl[t], acc, 0, 0, 0);
#pragma unroll
            for (int i = 0; i < 4; ++i)
                T[(q * 4 + i) * 66 + t * 16 + n16] = tanhf(acc[i]);
        }
        float b[16];
#pragma unroll
        for (int j = 0; j < 8; ++j) {
            b[j]     = T[n16 * 66 + q * 8 + j];
            b[8 + j] = T[n16 * 66 + 32 + q * 8 + j];
        }
        short8 ah0, ah1, al0, al1;
#pragma unroll
        for (int j = 0; j < 8; ++j) {
            short h, l;
            splitT(b[j], h, l);      ah0[j] = h; al0[j] = l;
            splitT(b[8 + j], h, l);  ah1[j] = h; al1[j] = l;
        }
#pragma unroll
        for (int t = 0; t < 4; ++t) {
            f32x4 aa = (f32x4){bias1[t], bias1[t], bias1[t], bias1[t]};
            aa = __builtin_amdgcn_mfma_f32_16x16x32_bf16(ah0, th[t][0], aa, 0, 0, 0);
            aa = __builtin_amdgcn_mfma_f32_16x16x32_bf16(ah1, th[t][1], aa, 0, 0, 0);
            aa = __builtin_amdgcn_mfma_f32_16x16x32_bf16(al0, th[t][0], aa, 0, 0, 0);
            aa = __builtin_amdgcn_mfma_f32_16x16x32_bf16(al1, th[t][1], aa, 0, 0, 0);
            aa = __builtin_amdgcn_mfma_f32_16x16x32_bf16(ah0, tl[t][0], aa, 0, 0, 0);
            aa = __builtin_amdgcn_mfma_f32_16x16x32_bf16(ah1, tl[t][1], aa, 0, 0, 0);
            f32x4 bb = (f32x4){0.f, 0.f, 0.f, 0.f};
            bb = __builtin_amdgcn_mfma_f32_16x16x32_bf16(ah0, uh[t][0], bb, 0, 0, 0);
            bb = __builtin_amdgcn_mfma_f32_16x16x32_bf16(ah1, uh[t][1], bb, 0, 0, 0);
            bb = __builtin_amdgcn_mfma_f32_16x16x32_bf16(al0, uh[t][0], bb, 0, 0, 0);
            bb = __builtin_amdgcn_mfma_f32_16x16x32_bf16(al1, uh[t][1], bb, 0, 0, 0);
            bb = __builtin_amdgcn_mfma_f32_16x16x32_bf16(ah0, ul[t][0], bb, 0, 0, 0);
            bb = __builtin_amdgcn_mfma_f32_16x16x32_bf16(ah1, ul[t][1], bb, 0, 0, 0);
#pragma unroll
            for (int i = 0; i < 4; ++i) {
                size_t off = (size_t)(v0 + q * 4 + i) * 64 + t * 16 + n16;
                atab[off] = (_Float16)aa[i];
                btab[off] = (_Float16)bb[i];
            }
        }
    }
}

// persistent waves; R3 node loop; fp16 MFMA (fp32 acc, zero-C, bias after max);
// remainder-csr hoisted; in-loop one-ahead csr prefetch; setprio around MFMA.
__global__ __launch_bounds__(256) void k_edge_mlp(
        const int* __restrict__ ptr, const int* __restrict__ csr_row,
        const _Float16* __restrict__ atab, const _Float16* __restrict__ btab,
        const float* __restrict__ w2, const float* __restrict__ b2,
        const float* __restrict__ wg, _Float16* __restrict__ h2h, int n) {
    int lane = threadIdx.x & 63;
    int n16 = lane & 15, q = lane >> 4;

    f16x8 wh[4][2];
    float bias[4];
    float wgf[4][4];    // Wg2 rows {t*16+n16}, cols {q*4+jj}
#pragma unroll
    for (int t = 0; t < 4; ++t) {
        bias[t] = b2[t * 16 + n16];
#pragma unroll
        for (int jj = 0; jj < 4; ++jj)
            wgf[t][jj] = wg[(t * 16 + n16) * 16 + q * 4 + jj];
#pragma unroll
        for (int ck = 0; ck < 2; ++ck) {
            f16x8 hh;
#pragma unroll
            for (int j = 0; j < 8; ++j)
                hh[j] = (_Float16)w2[(ck * 32 + q * 8 + j) * 64 + t * 16 + n16];
            wh[t][ck] = hh;
        }
    }
    const f32x4 z4 = (f32x4){0.f, 0.f, 0.f, 0.f};

    int nwaves = gridDim.x * 4;
    int wid = blockIdx.x * 4 + (threadIdx.x >> 6);

    for (int c = wid; c < n; c += nwaves) {
        int st = ptr[c], ed = ptr[c + 1];
        const f16x8* a8 = (const f16x8*)(atab + (size_t)c * 64);
        f16x8 A0 = a8[q], A1 = a8[4 + q];
        float red[4] = {0.f, 0.f, 0.f, 0.f};   // init 0 folds relu + empty-segment-0

        int deg = ed - st;
        int nfull = deg >> 4;
        int rem = deg & 15;
        int remBase = st + (nfull << 4);
        // both csr levels issue up front (independent addresses)
        int rrem = (rem > 0 && n16 < rem) ? csr_row[remBase + n16] : 0;
        int r = (nfull > 0) ? csr_row[st + n16] : 0;

        for (int ft = 0; ft < nfull; ++ft) {
            int rcur = r;
            if (ft + 1 < nfull) r = csr_row[st + (ft + 1) * 16 + n16];
            const f16x8* b8 = (const f16x8*)(btab + (size_t)rcur * 64);
            f16x8 u0 = relu8(A0 + b8[q]);
            f16x8 u1 = relu8(A1 + b8[4 + q]);
            __builtin_amdgcn_s_setprio(1);
#pragma unroll
            for (int t = 0; t < 4; ++t) {
                f32x4 a = __builtin_amdgcn_mfma_f32_16x16x32_f16(u0, wh[t][0], z4, 0, 0, 0);
                a = __builtin_amdgcn_mfma_f32_16x16x32_f16(u1, wh[t][1], a, 0, 0, 0);
                float mx = fmaxf(fmaxf(a[0], a[1]), fmaxf(a[2], a[3]));
                red[t] = fmaxf(red[t], mx + bias[t]);
            }
            __builtin_amdgcn_s_setprio(0);
        }
        if (rem > 0) {
            f16x8 u0 = {0, 0, 0, 0, 0, 0, 0, 0};
            f16x8 u1 = {0, 0, 0, 0, 0, 0, 0, 0};
            if (n16 < rem) {
                const f16x8* b8 = (const f16x8*)(btab + (size_t)rrem * 64);
                u0 = relu8(A0 + b8[q]);
                u1 = relu8(A1 + b8[4 + q]);
            }
            __builtin_amdgcn_s_setprio(1);
#pragma unroll
            for (int t = 0; t < 4; ++t) {
                f32x4 a = __builtin_amdgcn_mfma_f32_16x16x32_f16(u0, wh[t][0], z4, 0, 0, 0);
                a = __builtin_amdgcn_mfma_f32_16x16x32_f16(u1, wh[t][1], a, 0, 0, 0);
#pragma unroll
                for (int i = 0; i < 4; ++i)
                    if (q * 4 + i < rem) red[t] = fmaxf(red[t], a[i] + bias[t]);
            }
            __builtin_amdgcn_s_setprio(0);
        }
        // butterfly: all lanes get final segment-max for features t*16+n16
#pragma unroll
        for (int t = 0; t < 4; ++t) {
            red[t] = fmaxf(red[t], __shfl_xor(red[t], 16));
            red[t] = fmaxf(red[t], __shfl_xor(red[t], 32));
        }
        // fused GCN2 node matmul: h2[c][q*4+jj] = sum_d hmax[d]*wg[d][q*4+jj]
        float part[4];
#pragma unroll
        for (int jj = 0; jj < 4; ++jj) {
            part[jj] = red[0] * wgf[0][jj];
            part[jj] = fmaf(red[1], wgf[1][jj], part[jj]);
            part[jj] = fmaf(red[2], wgf[2][jj], part[jj]);
            part[jj] = fmaf(red[3], wgf[3][jj], part[jj]);
            // 16-lane rotate-add tree (full sum in every lane), DPP row_ror
            ROR_ADD(part[jj], 0x121);
            ROR_ADD(part[jj], 0x122);
            ROR_ADD(part[jj], 0x124);
            ROR_ADD(part[jj], 0x128);
        }
        if (n16 == 0) {
            f16x4 ph;
            ph[0] = (_Float16)part[0]; ph[1] = (_Float16)part[1];
            ph[2] = (_Float16)part[2]; ph[3] = (_Float16)part[3];
            ((f16x4*)(h2h + (size_t)c * 16))[q] = ph;
        }
    }
}

// out[c] = bg + dv*(dv*h2[c] + sum_in dinv[r]*h2[r]) ; fully writes d_out
__global__ __launch_bounds__(256) void k_gcn2_gather(
        const int* __restrict__ ptr, const int* __restrict__ csr_row,
        const _Float16* __restrict__ h2h, const float* __restrict__ dinv,
        const float* __restrict__ bg, float* __restrict__ out, int n) {
    int wid = blockIdx.x * 4 + (threadIdx.x >> 6);
    if (wid >= n) return;
    int lane = threadIdx.x & 63;
    int f2 = lane & 7, slot = lane >> 3;
    int c = wid;
    int start = ptr[c], end = ptr[c + 1];
    const f16x2* h22 = (const f16x2*)h2h;
    float sx = 0.f, sy = 0.f;
    int p = start + slot;
    int r = (p < end) ? csr_row[p] : 0;
    while (p < end) {
        int rcur = r;
        int pn = p + 8;
        if (pn < end) r = csr_row[pn];
        float dr = dinv[rcur];
        f16x2 hv = h22[(size_t)rcur * 8 + f2];
        sx = fmaf(dr, (float)hv[0], sx);
        sy = fmaf(dr, (float)hv[1], sy);
        p = pn;
    }
    ROR8_ADD(sx); ROR8_ADD(sy);
#pragma unroll
    for (int off = 16; off < 64; off <<= 1) {
        sx += __shfl_xor(sx, off);
        sy += __shfl_xor(sy, off);
    }
    if (slot == 0) {
        float dv = dinv[c];
        f16x2 hv = h22[(size_t)c * 8 + f2];
        float2 o;
        o.x = bg[2 * f2]     + dv * (dv * (float)hv[0] + sx);
        o.y = bg[2 * f2 + 1] + dv * (dv * (float)hv[1] + sy);
        ((float2*)out)[(size_t)c * 8 + f2] = o;
    }
}

extern "C" void kernel_launch(void* const* d_in, const int* in_sizes, int n_in,
                              void* d_out, int out_size, void* d_ws, size_t ws_size,
                              hipStream_t stream) {
    const float* x   = (const float*)d_in[0];
    const int*   ei  = (const int*)d_in[1];
    const float* g1w = (const float*)d_in[2];
    const float* g1b = (const float*)d_in[3];
    const float* ew1 = (const float*)d_in[4];
    const float* eb1 = (const float*)d_in[5];
    const float* ew2 = (const float*)d_in[6];
    const float* eb2 = (const float*)d_in[7];
    const float* g2w = (const float*)d_in[8];
    const float* g2b = (const float*)d_in[9];
    float* out = (float*)d_out;
    float* ws  = (float*)d_ws;

    const int n = in_sizes[0] / 32;      // 50000
    const int E = in_sizes[1] / 2;       // 800000
    const int* row = ei;
    const int* col = ei + E;
    const int ntiles = (n + 15) / 16;    // 3125
    const int nbuck = (n + 127) >> 7;    // 391 buckets of 128 cols

    size_t npad    = ((size_t)n + 63) & ~(size_t)63;
    size_t o_misc  = 0;                         // bbase[512]
    size_t o_ptr   = 1024;                      // n+1 (+pad)
    size_t o_csr   = o_ptr + npad + 64;         // E ints
    size_t o_dinv  = o_csr + (size_t)E;
    size_t o_atab  = o_dinv + npad;             // n*64 fp16 = n*32 floats
    size_t o_btab  = o_atab + (size_t)n * 32;   // n*64 fp16
    size_t o_agg   = o_btab + (size_t)n * 32;   // n*32 fp32
    size_t o_xh    = o_agg + (size_t)n * 32;    // n*32 fp16 = n*16 floats
    size_t o_h2h   = o_xh + (size_t)n * 16;     // n*16 fp16 = n*8 floats
    size_t o_stage = o_h2h + (size_t)n * 8;     // E ints (packed); pcnt aliases
    size_t o_bcur  = o_stage + (size_t)E * 2;   // nbuck ints

    int*      bbase  = (int*)(ws + o_misc);
    int*      ptr    = (int*)(ws + o_ptr);
    int*      csr    = (int*)(ws + o_csr);
    float*    dinv   = ws + o_dinv;
    _Float16* atab   = (_Float16*)(ws + o_atab);
    _Float16* btab   = (_Float16*)(ws + o_btab);
    float*    agg    = ws + o_agg;
    _Float16* xh     = (_Float16*)(ws + o_xh);
    _Float16* h2h    = (_Float16*)(ws + o_h2h);
    int*      stage  = (int*)(ws + o_stage);
    int*      pcnt   = (int*)(ws + o_stage);    // 196*512 ints, dead before fill_a
    int*      bcur   = (int*)(ws + o_bcur);

    int nblk = (n + 3) / 4;                      // wave-per-node kernels, 4 waves/block
    int fill_nb = (E + FILL_CH - 1) / FILL_CH;   // 196
    int m4 = n * 8;                              // x float4 count

    k_cast_count<<<fill_nb, 256, 0, stream>>>(col, (const float4*)x, (f16x4*)xh,
                                              pcnt, E, m4, nbuck);
    k_bucket_scan<<<1, 512, 0, stream>>>(pcnt, fill_nb, bbase, bcur, ptr, nbuck, n, E);
    k_fill_a<<<fill_nb, 256, 0, stream>>>(row, col, bcur, stage, E, nbuck);
    k_fill_b2<<<nbuck, 256, 0, stream>>>(bbase, bcur, stage, ptr, dinv, csr, n);
    k_gather32<<<nblk, 256, 0, stream>>>(ptr, csr, x, xh, dinv, agg, n);
    k_h1tab<<<256, 256, 0, stream>>>(agg, g1w, g1b, ew1, eb1, atab, btab, ntiles);
    k_edge_mlp<<<2048, 256, 0, stream>>>(ptr, csr, atab, btab, ew2, eb2, g2w, h2h, n);
    k_gcn2_gather<<<nblk, 256, 0, stream>>>(ptr, csr, h2h, dinv, g2b, out, n);
}

// Round 6
// 192.891 us; speedup vs baseline: 1.1809x; 1.1597x over previous
//
#include <hip/hip_runtime.h>

// CSR-gather pipeline (no float atomics):
//   memset(bcnt,2KB) ; fill_a (x->fp16 cast + fixed-slot bucket staging) ;
//   bucket_scan (1 blk, 512 reads) ; fill_b2 (per-bucket node hist + scan +
//   ptr/dinv/csr) ; gather32 ; h1tab ; edge_mlp (R5: csr hoist + zero-C MFMA +
//   setprio) ; gcn2_gather
// R6: R5's +23us regression isolated to bucket_scan's serial 196-chunk partial
//     sum (single block, ~900cy/chunk HBM-latency rounds). Fix: fixed 4096-slot
//     staging per bucket (mean 2048, sigma~45 -> 45-sigma headroom) so fill_a
//     self-allocates via (b<<12)+atomicAdd(bcnt) and NO histogram pre-pass over
//     col is needed at all; cast folds into fill_a. bucket_scan reads 512 ints.
//     edge_mlp/gather/h1tab/gcn2 unchanged from R5 (edge_mlp 43.0us, 56 VGPR).

typedef __attribute__((ext_vector_type(8))) short short8;
typedef __attribute__((ext_vector_type(4))) float f32x4;
typedef __attribute__((ext_vector_type(8))) _Float16 f16x8;
typedef __attribute__((ext_vector_type(4))) _Float16 f16x4;
typedef __attribute__((ext_vector_type(2))) _Float16 f16x2;

#define FILL_CH 4096      // edges per fill_a block (256 thr x 16)

__device__ __forceinline__ unsigned short f2bf(float x) {   // RNE f32->bf16 (cold paths only)
    unsigned int u = __float_as_uint(x);
    return (unsigned short)((u + 0x7FFFu + ((u >> 16) & 1u)) >> 16);
}
__device__ __forceinline__ float bf2f(unsigned short h) {
    return __uint_as_float(((unsigned int)h) << 16);
}
// cheap truncation split: u ~= hi + lo with |err| ~ 2^-16 |u|
__device__ __forceinline__ void splitT(float u, short& hi, short& lo) {
    unsigned int ub = __float_as_uint(u);
    hi = (short)(ub >> 16);
    float r = u - __uint_as_float(ub & 0xFFFF0000u);
    lo = (short)(__float_as_uint(r) >> 16);
}
__device__ __forceinline__ f16x8 relu8(f16x8 v) {
    f16x8 z = {0, 0, 0, 0, 0, 0, 0, 0};
#if __has_builtin(__builtin_elementwise_max)
    return __builtin_elementwise_max(v, z);
#else
    f16x8 o;
#pragma unroll
    for (int j = 0; j < 8; ++j) o[j] = v[j] > (_Float16)0 ? v[j] : (_Float16)0;
    return o;
#endif
}

// rotate-add within a 16-lane row (DPP row_ror:N); tree 1,2,4,8 == full 16-lane
// sum in every lane. Pure VALU. (row_ror = 0x120+N.)
#define ROR_ADD(s, CTRL)                                                         \
    s += __int_as_float(__builtin_amdgcn_update_dpp(                             \
        0, __float_as_int(s), (CTRL), 0xf, 0xf, false))
#define ROR8_ADD(s) ROR_ADD(s, 0x128)

// fill phase A (+ x->fp16 cast): bucket edges into FIXED 4096-entry slots.
// stage entry packed: (r << 7) | (c & 127)   [valid for n < 2^25]
__global__ __launch_bounds__(256) void k_fill_a(
        const int* __restrict__ row, const int* __restrict__ col,
        const float4* __restrict__ x4, f16x4* __restrict__ xh4,
        int* __restrict__ bcnt, int* __restrict__ stage, int E, int m4, int nb) {
    __shared__ int cnt[512];
    __shared__ int base[512];
    int tid = threadIdx.x;
    // independent grid-stride cast (fills xh for gather32)
    int nth = gridDim.x * 256;
    for (int idx = blockIdx.x * 256 + tid; idx < m4; idx += nth) {
        float4 v = x4[idx];
        f16x4 o;
        o[0] = (_Float16)v.x; o[1] = (_Float16)v.y;
        o[2] = (_Float16)v.z; o[3] = (_Float16)v.w;
        xh4[idx] = o;
    }
    for (int i = tid; i < nb; i += 256) cnt[i] = 0;
    __syncthreads();
    int e0 = blockIdx.x * FILL_CH;
    int r[16], c[16];
#pragma unroll
    for (int i = 0; i < 16; ++i) {
        int e = e0 + tid + i * 256;
        if (e < E) {
            r[i] = row[e]; c[i] = col[e];
            atomicAdd(&cnt[c[i] >> 7], 1);
        } else c[i] = -1;
    }
    __syncthreads();
    for (int i = tid; i < nb; i += 256)
        base[i] = cnt[i] ? (i << 12) + atomicAdd(&bcnt[i], cnt[i]) : 0;
    __syncthreads();
    for (int i = tid; i < nb; i += 256) cnt[i] = 0;
    __syncthreads();
#pragma unroll
    for (int i = 0; i < 16; ++i) {
        if (c[i] >= 0) {
            int b = c[i] >> 7;
            int lp = atomicAdd(&cnt[b], 1);
            stage[base[b] + lp] = (r[i] << 7) | (c[i] & 127);
        }
    }
}

// single block: exclusive scan of nb (<=512) bucket totals -> bbase (csr bases)
__global__ __launch_bounds__(512) void k_bucket_scan(
        const int* __restrict__ bcnt, int* __restrict__ bbase,
        int* __restrict__ ptr, int nb, int n, int E) {
    __shared__ int wt[8];
    int tid = threadIdx.x;
    int lane = tid & 63, w = tid >> 6;
    int v = (tid < nb) ? bcnt[tid] : 0;
    int s = v;
    for (int off = 1; off < 64; off <<= 1) {
        int t = __shfl_up(s, off, 64);
        if (lane >= off) s += t;
    }
    if (lane == 63) wt[w] = s;
    __syncthreads();
    int pre = 0;
    for (int i = 0; i < 8; ++i) if (i < w) pre += wt[i];
    if (tid < nb) bbase[tid] = pre + s - v;
    if (tid == 0) ptr[n] = E;
}

// fill phase B2: one block per bucket; local 128-col hist + exclusive scan
// produces ptr/dinv for this bucket's nodes, then scatters csr via LDS cursors.
__global__ __launch_bounds__(256) void k_fill_b2(
        const int* __restrict__ bcnt, const int* __restrict__ bbase,
        const int* __restrict__ stage, int* __restrict__ ptr,
        float* __restrict__ dinv, int* __restrict__ csr, int n) {
    __shared__ int lcnt[128];
    __shared__ int lcur[128];
    __shared__ int wtotS;
    int b = blockIdx.x, tid = threadIdx.x;
    int c0 = b << 7;
    int s0 = b << 12;               // fixed staging slot base
    int tot = bcnt[b];
    int gbase = bbase[b];           // global csr base for this bucket
    if (tid < 128) lcnt[tid] = 0;
    __syncthreads();
    for (int p = tid; p < tot; p += 256)
        atomicAdd(&lcnt[stage[s0 + p] & 127], 1);
    __syncthreads();
    int lane = tid & 63, w = tid >> 6;
    int v = (tid < 128) ? lcnt[tid] : 0;
    int s = v;
    for (int off = 1; off < 64; off <<= 1) {
        int t = __shfl_up(s, off, 64);
        if (lane >= off) s += t;
    }
    if (tid == 63) wtotS = s;
    __syncthreads();
    int excl = s - v + ((w == 1) ? wtotS : 0);
    if (tid < 128) {
        int c = c0 + tid;
        int basep = gbase + excl;
        lcur[tid] = basep;
        if (c < n) {
            ptr[c] = basep;
            dinv[c] = rsqrtf((float)(v + 1));   // +1 self loop
        }
    }
    __syncthreads();
    for (int p = tid; p < tot; p += 256) {
        int vv = stage[s0 + p];
        int pos = atomicAdd(&lcur[vv & 127], 1);
        csr[pos] = vv >> 7;
    }
}

// irregular gather (fp16 x): agg[v] = dv*(sum dinv[r]*xh[r]) + dv^2*x[v]
__global__ __launch_bounds__(256) void k_gather32(
        const int* __restrict__ ptr, const int* __restrict__ csr_row,
        const float* __restrict__ x, const _Float16* __restrict__ xh,
        const float* __restrict__ dinv, float* __restrict__ agg, int n) {
    int wid = blockIdx.x * 4 + (threadIdx.x >> 6);
    if (wid >= n) return;
    int lane = threadIdx.x & 63;
    int f4 = lane & 7, slot = lane >> 3;
    int v = wid;
    int start = ptr[v], end = ptr[v + 1];
    const f16x4* xh4 = (const f16x4*)xh;
    float sx = 0.f, sy = 0.f, sz = 0.f, sw = 0.f;
    int p = start + slot;
    int r = (p < end) ? csr_row[p] : 0;
    while (p < end) {
        int rcur = r;
        int pn = p + 8;
        if (pn < end) r = csr_row[pn];
        float dr = dinv[rcur];
        f16x4 xv = xh4[(size_t)rcur * 8 + f4];
        sx = fmaf(dr, (float)xv[0], sx);
        sy = fmaf(dr, (float)xv[1], sy);
        sz = fmaf(dr, (float)xv[2], sz);
        sw = fmaf(dr, (float)xv[3], sw);
        p = pn;
    }
    ROR8_ADD(sx); ROR8_ADD(sy); ROR8_ADD(sz); ROR8_ADD(sw);
#pragma unroll
    for (int off = 16; off < 64; off <<= 1) {
        sx += __shfl_xor(sx, off); sy += __shfl_xor(sy, off);
        sz += __shfl_xor(sz, off); sw += __shfl_xor(sw, off);
    }
    if (slot == 0) {
        float dv = dinv[v], d2 = dv * dv;
        float4 xv = ((const float4*)x)[(size_t)v * 8 + f4];
        float4 o;
        o.x = dv * sx + d2 * xv.x;
        o.y = dv * sy + d2 * xv.y;
        o.z = dv * sz + d2 * xv.z;
        o.w = dv * sw + d2 * xv.w;
        ((float4*)agg)[(size_t)v * 8 + f4] = o;
    }
}

// FUSED dense MFMA: h1 = tanh(agg @ Wg1 + gb) ; atab = h1@(W1a-W1b)+b1 ;
// btab = h1@W1b (fp16 out). Wave-private LDS tile for C/D->A transform.
__global__ __launch_bounds__(256, 1) void k_h1tab(
        const float* __restrict__ agg, const float* __restrict__ gw,
        const float* __restrict__ gb, const float* __restrict__ w1,
        const float* __restrict__ b1,
        _Float16* __restrict__ atab, _Float16* __restrict__ btab, int ntiles) {
    __shared__ float tileS[4][16 * 66];
    int lane = threadIdx.x & 63;
    int wv = threadIdx.x >> 6;
    int n16 = lane & 15, q = lane >> 4;
    float* T = tileS[wv];

    short8 gh[4], gl[4];
    float gbias[4];
#pragma unroll
    for (int t = 0; t < 4; ++t) {
        gbias[t] = gb[t * 16 + n16];
        short8 hh, ll;
#pragma unroll
        for (int j = 0; j < 8; ++j) {
            float w = gw[(q * 8 + j) * 64 + t * 16 + n16];
            unsigned short wh = f2bf(w);
            hh[j] = (short)wh;
            ll[j] = (short)f2bf(w - bf2f(wh));
        }
        gh[t] = hh; gl[t] = ll;
    }
    short8 th[4][2], tl[4][2], uh[4][2], ul[4][2];
    float bias1[4];
#pragma unroll
    for (int t = 0; t < 4; ++t) {
        bias1[t] = b1[t * 16 + n16];
#pragma unroll
        for (int ck = 0; ck < 2; ++ck) {
            short8 h1v, l1v, h2v, l2v;
#pragma unroll
            for (int j = 0; j < 8; ++j) {
                int d = ck * 32 + q * 8 + j;
                float wbv = w1[(64 + d) * 64 + t * 16 + n16];
                float wtv = w1[d * 64 + t * 16 + n16] - wbv;
                unsigned short x1 = f2bf(wtv);
                h1v[j] = (short)x1; l1v[j] = (short)f2bf(wtv - bf2f(x1));
                unsigned short x2 = f2bf(wbv);
                h2v[j] = (short)x2; l2v[j] = (short)f2bf(wbv - bf2f(x2));
            }
            th[t][ck] = h1v; tl[t][ck] = l1v;
            uh[t][ck] = h2v; ul[t][ck] = l2v;
        }
    }

    int nwaves = gridDim.x * 4;
    int wid = blockIdx.x * 4 + wv;
    for (int tile = wid; tile < ntiles; tile += nwaves) {
        int v0 = tile * 16;
        const float4* a4 = (const float4*)(agg + (size_t)(v0 + n16) * 32);
        float4 A0 = a4[2 * q], A1 = a4[2 * q + 1];
        float a[8] = {A0.x, A0.y, A0.z, A0.w, A1.x, A1.y, A1.z, A1.w};
        short8 ah, al;
#pragma unroll
        for (int j = 0; j < 8; ++j) { short h, l; splitT(a[j], h, l); ah[j] = h; al[j] = l; }
#pragma unroll
        for (int t = 0; t < 4; ++t) {
            f32x4 acc = (f32x4){gbias[t], gbias[t], gbias[t], gbias[t]};
            acc = __builtin_amdgcn_mfma_f32_16x16x32_bf16(ah, gh[t], acc, 0, 0, 0);
            acc = __builtin_amdgcn_mfma_f32_16x16x32_bf16(al, gh[t], acc, 0, 0, 0);
            acc = __builtin_amdgcn_mfma_f32_16x16x32_bf16(ah, gl[t], acc, 0, 0, 0);
#pragma unroll
            for (int i = 0; i < 4; ++i)
                T[(q * 4 + i) * 66 + t * 16 + n16] = tanhf(acc[i]);
        }
        float b[16];
#pragma unroll
        for (int j = 0; j < 8; ++j) {
            b[j]     = T[n16 * 66 + q * 8 + j];
            b[8 + j] = T[n16 * 66 + 32 + q * 8 + j];
        }
        short8 ah0, ah1, al0, al1;
#pragma unroll
        for (int j = 0; j < 8; ++j) {
            short h, l;
            splitT(b[j], h, l);      ah0[j] = h; al0[j] = l;
            splitT(b[8 + j], h, l);  ah1[j] = h; al1[j] = l;
        }
#pragma unroll
        for (int t = 0; t < 4; ++t) {
            f32x4 aa = (f32x4){bias1[t], bias1[t], bias1[t], bias1[t]};
            aa = __builtin_amdgcn_mfma_f32_16x16x32_bf16(ah0, th[t][0], aa, 0, 0, 0);
            aa = __builtin_amdgcn_mfma_f32_16x16x32_bf16(ah1, th[t][1], aa, 0, 0, 0);
            aa = __builtin_amdgcn_mfma_f32_16x16x32_bf16(al0, th[t][0], aa, 0, 0, 0);
            aa = __builtin_amdgcn_mfma_f32_16x16x32_bf16(al1, th[t][1], aa, 0, 0, 0);
            aa = __builtin_amdgcn_mfma_f32_16x16x32_bf16(ah0, tl[t][0], aa, 0, 0, 0);
            aa = __builtin_amdgcn_mfma_f32_16x16x32_bf16(ah1, tl[t][1], aa, 0, 0, 0);
            f32x4 bb = (f32x4){0.f, 0.f, 0.f, 0.f};
            bb = __builtin_amdgcn_mfma_f32_16x16x32_bf16(ah0, uh[t][0], bb, 0, 0, 0);
            bb = __builtin_amdgcn_mfma_f32_16x16x32_bf16(ah1, uh[t][1], bb, 0, 0, 0);
            bb = __builtin_amdgcn_mfma_f32_16x16x32_bf16(al0, uh[t][0], bb, 0, 0, 0);
            bb = __builtin_amdgcn_mfma_f32_16x16x32_bf16(al1, uh[t][1], bb, 0, 0, 0);
            bb = __builtin_amdgcn_mfma_f32_16x16x32_bf16(ah0, ul[t][0], bb, 0, 0, 0);
            bb = __builtin_amdgcn_mfma_f32_16x16x32_bf16(ah1, ul[t][1], bb, 0, 0, 0);
#pragma unroll
            for (int i = 0; i < 4; ++i) {
                size_t off = (size_t)(v0 + q * 4 + i) * 64 + t * 16 + n16;
                atab[off] = (_Float16)aa[i];
                btab[off] = (_Float16)bb[i];
            }
        }
    }
}

// persistent waves; R3 node loop; fp16 MFMA (fp32 acc, zero-C, bias after max);
// remainder-csr hoisted; in-loop one-ahead csr prefetch; setprio around MFMA.
__global__ __launch_bounds__(256) void k_edge_mlp(
        const int* __restrict__ ptr, const int* __restrict__ csr_row,
        const _Float16* __restrict__ atab, const _Float16* __restrict__ btab,
        const float* __restrict__ w2, const float* __restrict__ b2,
        const float* __restrict__ wg, _Float16* __restrict__ h2h, int n) {
    int lane = threadIdx.x & 63;
    int n16 = lane & 15, q = lane >> 4;

    f16x8 wh[4][2];
    float bias[4];
    float wgf[4][4];    // Wg2 rows {t*16+n16}, cols {q*4+jj}
#pragma unroll
    for (int t = 0; t < 4; ++t) {
        bias[t] = b2[t * 16 + n16];
#pragma unroll
        for (int jj = 0; jj < 4; ++jj)
            wgf[t][jj] = wg[(t * 16 + n16) * 16 + q * 4 + jj];
#pragma unroll
        for (int ck = 0; ck < 2; ++ck) {
            f16x8 hh;
#pragma unroll
            for (int j = 0; j < 8; ++j)
                hh[j] = (_Float16)w2[(ck * 32 + q * 8 + j) * 64 + t * 16 + n16];
            wh[t][ck] = hh;
        }
    }
    const f32x4 z4 = (f32x4){0.f, 0.f, 0.f, 0.f};

    int nwaves = gridDim.x * 4;
    int wid = blockIdx.x * 4 + (threadIdx.x >> 6);

    for (int c = wid; c < n; c += nwaves) {
        int st = ptr[c], ed = ptr[c + 1];
        const f16x8* a8 = (const f16x8*)(atab + (size_t)c * 64);
        f16x8 A0 = a8[q], A1 = a8[4 + q];
        float red[4] = {0.f, 0.f, 0.f, 0.f};   // init 0 folds relu + empty-segment-0

        int deg = ed - st;
        int nfull = deg >> 4;
        int rem = deg & 15;
        int remBase = st + (nfull << 4);
        // both csr levels issue up front (independent addresses)
        int rrem = (rem > 0 && n16 < rem) ? csr_row[remBase + n16] : 0;
        int r = (nfull > 0) ? csr_row[st + n16] : 0;

        for (int ft = 0; ft < nfull; ++ft) {
            int rcur = r;
            if (ft + 1 < nfull) r = csr_row[st + (ft + 1) * 16 + n16];
            const f16x8* b8 = (const f16x8*)(btab + (size_t)rcur * 64);
            f16x8 u0 = relu8(A0 + b8[q]);
            f16x8 u1 = relu8(A1 + b8[4 + q]);
            __builtin_amdgcn_s_setprio(1);
#pragma unroll
            for (int t = 0; t < 4; ++t) {
                f32x4 a = __builtin_amdgcn_mfma_f32_16x16x32_f16(u0, wh[t][0], z4, 0, 0, 0);
                a = __builtin_amdgcn_mfma_f32_16x16x32_f16(u1, wh[t][1], a, 0, 0, 0);
                float mx = fmaxf(fmaxf(a[0], a[1]), fmaxf(a[2], a[3]));
                red[t] = fmaxf(red[t], mx + bias[t]);
            }
            __builtin_amdgcn_s_setprio(0);
        }
        if (rem > 0) {
            f16x8 u0 = {0, 0, 0, 0, 0, 0, 0, 0};
            f16x8 u1 = {0, 0, 0, 0, 0, 0, 0, 0};
            if (n16 < rem) {
                const f16x8* b8 = (const f16x8*)(btab + (size_t)rrem * 64);
                u0 = relu8(A0 + b8[q]);
                u1 = relu8(A1 + b8[4 + q]);
            }
            __builtin_amdgcn_s_setprio(1);
#pragma unroll
            for (int t = 0; t < 4; ++t) {
                f32x4 a = __builtin_amdgcn_mfma_f32_16x16x32_f16(u0, wh[t][0], z4, 0, 0, 0);
                a = __builtin_amdgcn_mfma_f32_16x16x32_f16(u1, wh[t][1], a, 0, 0, 0);
#pragma unroll
                for (int i = 0; i < 4; ++i)
                    if (q * 4 + i < rem) red[t] = fmaxf(red[t], a[i] + bias[t]);
            }
            __builtin_amdgcn_s_setprio(0);
        }
        // butterfly: all lanes get final segment-max for features t*16+n16
#pragma unroll
        for (int t = 0; t < 4; ++t) {
            red[t] = fmaxf(red[t], __shfl_xor(red[t], 16));
            red[t] = fmaxf(red[t], __shfl_xor(red[t], 32));
        }
        // fused GCN2 node matmul: h2[c][q*4+jj] = sum_d hmax[d]*wg[d][q*4+jj]
        float part[4];
#pragma unroll
        for (int jj = 0; jj < 4; ++jj) {
            part[jj] = red[0] * wgf[0][jj];
            part[jj] = fmaf(red[1], wgf[1][jj], part[jj]);
            part[jj] = fmaf(red[2], wgf[2][jj], part[jj]);
            part[jj] = fmaf(red[3], wgf[3][jj], part[jj]);
            // 16-lane rotate-add tree (full sum in every lane), DPP row_ror
            ROR_ADD(part[jj], 0x121);
            ROR_ADD(part[jj], 0x122);
            ROR_ADD(part[jj], 0x124);
            ROR_ADD(part[jj], 0x128);
        }
        if (n16 == 0) {
            f16x4 ph;
            ph[0] = (_Float16)part[0]; ph[1] = (_Float16)part[1];
            ph[2] = (_Float16)part[2]; ph[3] = (_Float16)part[3];
            ((f16x4*)(h2h + (size_t)c * 16))[q] = ph;
        }
    }
}

// out[c] = bg + dv*(dv*h2[c] + sum_in dinv[r]*h2[r]) ; fully writes d_out
__global__ __launch_bounds__(256) void k_gcn2_gather(
        const int* __restrict__ ptr, const int* __restrict__ csr_row,
        const _Float16* __restrict__ h2h, const float* __restrict__ dinv,
        const float* __restrict__ bg, float* __restrict__ out, int n) {
    int wid = blockIdx.x * 4 + (threadIdx.x >> 6);
    if (wid >= n) return;
    int lane = threadIdx.x & 63;
    int f2 = lane & 7, slot = lane >> 3;
    int c = wid;
    int start = ptr[c], end = ptr[c + 1];
    const f16x2* h22 = (const f16x2*)h2h;
    float sx = 0.f, sy = 0.f;
    int p = start + slot;
    int r = (p < end) ? csr_row[p] : 0;
    while (p < end) {
        int rcur = r;
        int pn = p + 8;
        if (pn < end) r = csr_row[pn];
        float dr = dinv[rcur];
        f16x2 hv = h22[(size_t)rcur * 8 + f2];
        sx = fmaf(dr, (float)hv[0], sx);
        sy = fmaf(dr, (float)hv[1], sy);
        p = pn;
    }
    ROR8_ADD(sx); ROR8_ADD(sy);
#pragma unroll
    for (int off = 16; off < 64; off <<= 1) {
        sx += __shfl_xor(sx, off);
        sy += __shfl_xor(sy, off);
    }
    if (slot == 0) {
        float dv = dinv[c];
        f16x2 hv = h22[(size_t)c * 8 + f2];
        float2 o;
        o.x = bg[2 * f2]     + dv * (dv * (float)hv[0] + sx);
        o.y = bg[2 * f2 + 1] + dv * (dv * (float)hv[1] + sy);
        ((float2*)out)[(size_t)c * 8 + f2] = o;
    }
}

extern "C" void kernel_launch(void* const* d_in, const int* in_sizes, int n_in,
                              void* d_out, int out_size, void* d_ws, size_t ws_size,
                              hipStream_t stream) {
    const float* x   = (const float*)d_in[0];
    const int*   ei  = (const int*)d_in[1];
    const float* g1w = (const float*)d_in[2];
    const float* g1b = (const float*)d_in[3];
    const float* ew1 = (const float*)d_in[4];
    const float* eb1 = (const float*)d_in[5];
    const float* ew2 = (const float*)d_in[6];
    const float* eb2 = (const float*)d_in[7];
    const float* g2w = (const float*)d_in[8];
    const float* g2b = (const float*)d_in[9];
    float* out = (float*)d_out;
    float* ws  = (float*)d_ws;

    const int n = in_sizes[0] / 32;      // 50000
    const int E = in_sizes[1] / 2;       // 800000
    const int* row = ei;
    const int* col = ei + E;
    const int ntiles = (n + 15) / 16;    // 3125
    const int nbuck = (n + 127) >> 7;    // 391 buckets of 128 cols

    size_t npad    = ((size_t)n + 63) & ~(size_t)63;
    size_t o_misc  = 0;                         // bcnt[512] + bbase[512]
    size_t o_ptr   = 1024;                      // n+1 (+pad)
    size_t o_csr   = o_ptr + npad + 64;         // E ints
    size_t o_dinv  = o_csr + (size_t)E;
    size_t o_atab  = o_dinv + npad;             // n*64 fp16 = n*32 floats
    size_t o_btab  = o_atab + (size_t)n * 32;   // n*64 fp16
    size_t o_agg   = o_btab + (size_t)n * 32;   // n*32 fp32
    size_t o_xh    = o_agg + (size_t)n * 32;    // n*32 fp16 = n*16 floats
    size_t o_h2h   = o_xh + (size_t)n * 16;     // n*16 fp16 = n*8 floats
    size_t o_stage = o_h2h + (size_t)n * 8;     // nbuck*4096 ints (fixed slots)

    int*      bcnt   = (int*)(ws + o_misc);
    int*      bbase  = (int*)(ws + o_misc) + 512;
    int*      ptr    = (int*)(ws + o_ptr);
    int*      csr    = (int*)(ws + o_csr);
    float*    dinv   = ws + o_dinv;
    _Float16* atab   = (_Float16*)(ws + o_atab);
    _Float16* btab   = (_Float16*)(ws + o_btab);
    float*    agg    = ws + o_agg;
    _Float16* xh     = (_Float16*)(ws + o_xh);
    _Float16* h2h    = (_Float16*)(ws + o_h2h);
    int*      stage  = (int*)(ws + o_stage);

    int nblk = (n + 3) / 4;                      // wave-per-node kernels, 4 waves/block
    int fill_nb = (E + FILL_CH - 1) / FILL_CH;   // 196
    int m4 = n * 8;                              // x float4 count

    hipMemsetAsync(bcnt, 0, 512 * sizeof(int), stream);
    k_fill_a<<<fill_nb, 256, 0, stream>>>(row, col, (const float4*)x, (f16x4*)xh,
                                          bcnt, stage, E, m4, nbuck);
    k_bucket_scan<<<1, 512, 0, stream>>>(bcnt, bbase, ptr, nbuck, n, E);
    k_fill_b2<<<nbuck, 256, 0, stream>>>(bcnt, bbase, stage, ptr, dinv, csr, n);
    k_gather32<<<nblk, 256, 0, stream>>>(ptr, csr, x, xh, dinv, agg, n);
    k_h1tab<<<256, 256, 0, stream>>>(agg, g1w, g1b, ew1, eb1, atab, btab, ntiles);
    k_edge_mlp<<<2048, 256, 0, stream>>>(ptr, csr, atab, btab, ew2, eb2, g2w, h2h, n);
    k_gcn2_gather<<<nblk, 256, 0, stream>>>(ptr, csr, h2h, dinv, g2b, out, n);
}